// Round 2
// baseline (366.072 us; speedup 1.0000x reference)
//
#include <hip/hip_runtime.h>
#include <math.h>

// EdgeFeaturizer: per-row top-12 smallest of 8192x8192 fp32 + 50-bin RBF.
// d_out (float32): [8192*12*2] edge_index encoded as floats, then
// [8192*12*50] features.
//
// Wave-per-row design: one 64-lane wave scans one row (32 float4 loads/lane),
// compacts candidates d < CAND_T via ballot+popc prefix (no atomics), then
// O(count^2) rank-select on ~82 keys with LDS broadcast reads. Key =
// (float_bits<<32)|idx gives exactly top_k's (dist asc, idx asc) order.
// Exact per-wave fallback (12 sequential masked min-reductions) guarantees
// correctness for any input; never taken for uniform [0,1) data.

#define N_ATOMS 8192
#define K 12
#define NBINS 50
#define CAP 256          // candidates/row ~ Binom(8192,0.01): mean 82, max<<256
#define WAVES 4
#define BLOCK (WAVES * 64)
#define MAX_RADIUS 8.0f
#define CAND_T 0.01f

__global__ __launch_bounds__(BLOCK) void edge_kernel(const float* __restrict__ dm,
                                                     float* __restrict__ out) {
    const int wave = threadIdx.x >> 6;
    const int lane = threadIdx.x & 63;
    const int row = blockIdx.x * WAVES + wave;
    const float* rowp = dm + (size_t)row * N_ATOMS;
    const float4* row4 = (const float4*)rowp;

    __shared__ unsigned long long s_keys[WAVES][CAP];
    __shared__ int s_selidx[WAVES][K];
    __shared__ float s_seldist[WAVES][K];

    const unsigned long long lane_below = (1ull << lane) - 1ull;

    // ---- scan: coalesced float4, ballot-compact candidates into LDS ----
    int count = 0;
    #pragma unroll 4
    for (int i = 0; i < N_ATOMS / (64 * 4); ++i) {   // 32 iterations
        int v4 = lane + i * 64;
        float4 v = row4[v4];
        int bidx = v4 * 4;
        float vals[4] = {v.x, v.y, v.z, v.w};
        #pragma unroll
        for (int c = 0; c < 4; ++c) {
            float d = vals[c];
            bool pred = d < CAND_T;
            unsigned long long m = __ballot(pred);
            if (pred) {
                int pos = count + __popcll(m & lane_below);
                if (pos < CAP)
                    s_keys[wave][pos] =
                        ((unsigned long long)__float_as_uint(d) << 32) |
                        (unsigned int)(bidx + c);
            }
            count += __popcll(m);
        }
    }
    __syncthreads();  // LDS write->read visibility (cheap; all waves reach)

    if (count >= K && count <= CAP) {
        // ---- rank select: rank = #keys strictly smaller (keys unique) ----
        for (int j = lane; j < count; j += 64) {
            unsigned long long kj = s_keys[wave][j];
            int rank = 0;
            for (int m2 = 0; m2 < count; ++m2)       // broadcast reads
                rank += (s_keys[wave][m2] < kj) ? 1 : 0;
            if (rank < K) {
                s_selidx[wave][rank] = (int)(kj & 0xFFFFFFFFull);
                s_seldist[wave][rank] =
                    __uint_as_float((unsigned int)(kj >> 32));
            }
        }
    } else {
        // ---- exact per-wave fallback (never taken on this input) ----
        unsigned long long last = 0ull;
        for (int r = 0; r < K; ++r) {
            unsigned long long best = ~0ull;
            for (int i = 0; i < N_ATOMS / (64 * 4); ++i) {
                int v4 = lane + i * 64;
                float4 v = row4[v4];   // L2-resident on re-scan
                int bidx = v4 * 4;
                float vals[4] = {v.x, v.y, v.z, v.w};
                #pragma unroll
                for (int c = 0; c < 4; ++c) {
                    float d = vals[c];
                    float md = (d <= MAX_RADIUS) ? d
                                                 : __uint_as_float(0x7F800000u);
                    unsigned long long key =
                        ((unsigned long long)__float_as_uint(md) << 32) |
                        (unsigned int)(bidx + c);
                    if (((r == 0) || (key > last)) && key < best) best = key;
                }
            }
            #pragma unroll
            for (int off = 32; off > 0; off >>= 1) {
                unsigned long long other = __shfl_xor(best, off, 64);
                if (other < best) best = other;
            }
            if (lane == 0) {
                int idx = (int)(best & 0xFFFFFFFFull);
                s_selidx[wave][r] = idx;
                s_seldist[wave][r] = rowp[idx];  // original dm value
            }
            last = best;
        }
    }

    // ---- outputs ----
    float* out_ei = out;
    float* out_ef = out + (size_t)N_ATOMS * K * 2;
    if (lane < 2 * K) {
        int r = lane >> 1, comp = lane & 1;
        out_ei[((size_t)row * K + r) * 2 + comp] =
            comp ? (float)s_selidx[wave][r] : (float)row;
    }
    for (int t = lane; t < K * NBINS; t += 64) {
        int r = t / NBINS, b = t - r * NBINS;
        float d = s_seldist[wave][r];
        float z = (d - (float)b * (1.0f / 49.0f)) * 5.0f;
        out_ef[(size_t)row * K * NBINS + t] = __expf(-0.5f * z * z);
    }
}

extern "C" void kernel_launch(void* const* d_in, const int* in_sizes, int n_in,
                              void* d_out, int out_size, void* d_ws, size_t ws_size,
                              hipStream_t stream) {
    const float* dm = (const float*)d_in[0];
    float* out = (float*)d_out;
    edge_kernel<<<N_ATOMS / WAVES, BLOCK, 0, stream>>>(dm, out);
}